// Round 5
// baseline (456.090 us; speedup 1.0000x reference)
//
#include <hip/hip_runtime.h>
#include <hip/hip_bf16.h>

#define BB 128
#define NN 4096
#define DD 64
#define SS 8
#define HH 128

typedef __attribute__((ext_vector_type(8))) short short8;
typedef __attribute__((ext_vector_type(4))) float f32x4;

__device__ __forceinline__ float warp_red_sum(float v) {
    #pragma unroll
    for (int off = 32; off; off >>= 1) v += __shfl_xor(v, off);
    return v;
}

__device__ __forceinline__ float bcastlane(float v, int l) {
    return __int_as_float(__builtin_amdgcn_readlane(__float_as_int(v), l));
}

__device__ __forceinline__ unsigned short bfu(float f) {
    __hip_bfloat16 h = __float2bfloat16(f);
    return *(unsigned short*)&h;
}

__device__ __forceinline__ unsigned pk2(float a, float b) {
    return (unsigned)bfu(a) | ((unsigned)bfu(b) << 16);
}

// ---------------- prep: small weight transposes ----------------
__global__ __launch_bounds__(256) void prep_kernel(
    const float* __restrict__ v_w, const float* __restrict__ q_w,
    const float* __restrict__ wih, const float* __restrict__ whh,
    const float* __restrict__ w1, const float* __restrict__ w2,
    float* __restrict__ vwT, float* __restrict__ qwT,
    float* __restrict__ wihT, float* __restrict__ whhT,
    float* __restrict__ w1T, float* __restrict__ w2T)
{
    int i0 = blockIdx.x * blockDim.x + threadIdx.x;
    int nthr = gridDim.x * blockDim.x;
    for (int t = i0; t < 4096; t += nthr) {
        int i = t >> 6, o = t & 63;
        vwT[t] = v_w[o * 64 + i];          // vwT[i][o]
        qwT[t] = q_w[o * 64 + i];          // qwT[i][o]
    }
    for (int t = i0; t < 12288; t += nthr) {
        int r = t / 192, c = t % 192;
        wihT[t] = wih[c * 64 + r];
        whhT[t] = whh[c * 64 + r];
    }
    for (int t = i0; t < 8192; t += nthr) {
        int r = t >> 7, c = t & 127;
        w1T[t] = w1[c * 64 + r];
    }
    for (int t = i0; t < 8192; t += nthr) {
        int r = t >> 6, c = t & 63;
        w2T[t] = w2[c * 128 + r];
    }
}

// ---------------- init: slots + q' (q·Wk/8) + zero numer0 ----------------
__global__ __launch_bounds__(256) void init_q_kernel(
    const float* __restrict__ eps, const float* __restrict__ mu,
    const float* __restrict__ lv, const float* __restrict__ qwT,
    const float* __restrict__ k_w,
    const float* __restrict__ nsw, const float* __restrict__ nsb,
    float* __restrict__ slots, unsigned short* __restrict__ qb,
    float* __restrict__ zbuf)
{
    const int tid = threadIdx.x, lane = tid & 63;
    const int row = blockIdx.x * 4 + (tid >> 6);     // 1024 rows = B*S
    const int idx = row * 64 + lane;
    float s0 = mu[lane] + __expf(0.5f * lv[lane]) * eps[idx];
    slots[idx] = s0;
    float m = warp_red_sum(s0) * (1.0f / 64.0f);
    float dx = s0 - m;
    float var = warp_red_sum(dx * dx) * (1.0f / 64.0f);
    float xln = dx * rsqrtf(var + 1e-5f) * nsw[lane] + nsb[lane];
    float q = 0.f;
    #pragma unroll 8
    for (int i = 0; i < 64; ++i) q = fmaf(bcastlane(xln, i), qwT[i * 64 + lane], q);
    float qp = 0.f;
    #pragma unroll 8
    for (int o = 0; o < 64; ++o) qp = fmaf(bcastlane(q, o), k_w[o * 64 + lane], qp);
    qb[idx] = bfu(qp * 0.125f);
    // zero numer0+denom0 (66560 floats)
    int g = blockIdx.x * 256 + tid;
    for (int j = g; j < 66560; j += 65536) zbuf[j] = 0.f;
}

// ---------------- phase A: streaming LN -> X bf16 [tok][d] and X^T bf16 [b][d][tok] ----------------
// 128 tokens/block, one barrier, ~17.4 KB LDS.
__global__ __launch_bounds__(256) void phase_a_ln(
    const float* __restrict__ inp, const float* __restrict__ niw, const float* __restrict__ nib,
    unsigned short* __restrict__ xb, unsigned short* __restrict__ xbt)
{
    __shared__ unsigned short xt[64 * 136];
    const int tid = threadIdx.x, lane = tid & 63, widx = tid >> 6;
    const int tg = lane >> 4, dq = lane & 15;
    const float4 wni = *(const float4*)&niw[dq * 4];
    const float4 bni = *(const float4*)&nib[dq * 4];
    const int tok0 = blockIdx.x * 128;
    #pragma unroll
    for (int it = 0; it < 8; ++it) {
        const int m = widx * 32 + it * 4 + tg;
        float4 x = *(const float4*)&inp[(size_t)(tok0 + m) * 64 + dq * 4];
        float s1 = x.x + x.y + x.z + x.w;
        float s2 = fmaf(x.x, x.x, fmaf(x.y, x.y, fmaf(x.z, x.z, x.w * x.w)));
        #pragma unroll
        for (int o = 1; o < 16; o <<= 1) { s1 += __shfl_xor(s1, o); s2 += __shfl_xor(s2, o); }
        float mean = s1 * (1.0f / 64.0f);
        float var = s2 * (1.0f / 64.0f) - mean * mean;
        float rstd = rsqrtf(var + 1e-5f);
        float y0 = (x.x - mean) * rstd * wni.x + bni.x;
        float y1 = (x.y - mean) * rstd * wni.y + bni.y;
        float y2 = (x.z - mean) * rstd * wni.z + bni.z;
        float y3 = (x.w - mean) * rstd * wni.w + bni.w;
        uint2 p; p.x = pk2(y0, y1); p.y = pk2(y2, y3);
        *(uint2*)&xb[(size_t)(tok0 + m) * 64 + dq * 4] = p;
        xt[(dq * 4 + 0) * 136 + m] = bfu(y0);
        xt[(dq * 4 + 1) * 136 + m] = bfu(y1);
        xt[(dq * 4 + 2) * 136 + m] = bfu(y2);
        xt[(dq * 4 + 3) * 136 + m] = bfu(y3);
    }
    __syncthreads();
    const int b = blockIdx.x >> 5, tin = (blockIdx.x & 31) * 128;
    const int d = tid >> 2, q4 = tid & 3;
    #pragma unroll
    for (int c = 0; c < 4; ++c) {
        uint4 o = *(uint4*)&xt[d * 136 + q4 * 32 + c * 8];
        *(uint4*)&xbt[((size_t)b * 64 + d) * 4096 + tin + q4 * 32 + c * 8] = o;
    }
}

// ---------------- attention via MFMA: X·q'^T -> softmax -> w^T·X (numerX) ----------------
__global__ __launch_bounds__(256) void attn_mfma(
    const __hip_bfloat16* __restrict__ xb, const unsigned short* __restrict__ xbt,
    const unsigned short* __restrict__ qb,
    float* __restrict__ numer, float* __restrict__ denom, float* __restrict__ wout)
{
    __shared__ unsigned short smem[24192];
    unsigned short* Qs = smem;                          // [16][72]
    const int tid = threadIdx.x, lane = tid & 63, widx = tid >> 6;
    unsigned short* wls = smem + 1152 + widx * 1152;    // [16][72]
    unsigned short* vt  = smem + 5760 + widx * 4608;    // [64][72]
    const int b = blockIdx.y;

    for (int t = tid; t < 1024; t += 256) {
        int s = t >> 6, dd = t & 63;
        Qs[s * 72 + dd] = (s < 8) ? qb[b * 512 + t] : (unsigned short)0;
    }
    for (int t = lane; t < 576; t += 64) wls[576 + t] = 0;
    __syncthreads();

    const int quad = lane >> 4, l16 = lane & 15;
    short8 bq0 = *(const short8*)&Qs[l16 * 72 + quad * 8];
    short8 bq1 = *(const short8*)&Qs[l16 * 72 + 32 + quad * 8];

    f32x4 accv[4];
    #pragma unroll
    for (int nt = 0; nt < 4; ++nt) accv[nt] = (f32x4){0.f, 0.f, 0.f, 0.f};
    float dsum = 0.f;

    const int twave0 = blockIdx.x * 512 + widx * 128;
    const int vd = lane >> 3, vc = (lane & 7) * 8;
    #pragma unroll
    for (int iter = 0; iter < 2; ++iter) {
        const int t0 = twave0 + iter * 64;
        uint4 vld[8];
        #pragma unroll
        for (int i = 0; i < 8; ++i)
            vld[i] = *(const uint4*)&xbt[((size_t)b * 64 + i * 8 + vd) * 4096 + t0 + vc];

        #pragma unroll
        for (int t4 = 0; t4 < 4; ++t4) {
            const size_t krow = ((size_t)b * NN + t0 + t4 * 16 + l16) * 64;
            short8 ak0 = *(const short8*)&xb[krow + quad * 8];
            short8 ak1 = *(const short8*)&xb[krow + 32 + quad * 8];
            f32x4 lg = (f32x4){0.f, 0.f, 0.f, 0.f};
            lg = __builtin_amdgcn_mfma_f32_16x16x32_bf16(ak0, bq0, lg, 0, 0, 0);
            lg = __builtin_amdgcn_mfma_f32_16x16x32_bf16(ak1, bq1, lg, 0, 0, 0);
            float wv[4];
            #pragma unroll
            for (int r = 0; r < 4; ++r) {
                float e = __expf(lg[r]);
                float s = e;
                s += __shfl_xor(s, 1); s += __shfl_xor(s, 2); s += __shfl_xor(s, 4);
                wv[r] = e / s + 1e-8f;
                dsum += wv[r];
            }
            if (l16 < 8) {
                *(unsigned*)&wls[l16 * 72 + t4 * 16 + quad * 4]     = pk2(wv[0], wv[1]);
                *(unsigned*)&wls[l16 * 72 + t4 * 16 + quad * 4 + 2] = pk2(wv[2], wv[3]);
                if (wout) {
                    float* wp = wout + ((size_t)b * NN + t0 + t4 * 16 + quad * 4) * 8 + l16;
                    wp[0] = wv[0]; wp[8] = wv[1]; wp[16] = wv[2]; wp[24] = wv[3];
                }
            }
        }
        #pragma unroll
        for (int i = 0; i < 8; ++i)
            *(uint4*)&vt[(i * 8 + vd) * 72 + vc] = vld[i];
        #pragma unroll
        for (int ks = 0; ks < 2; ++ks) {
            short8 aw = *(const short8*)&wls[l16 * 72 + ks * 32 + quad * 8];
            #pragma unroll
            for (int nt = 0; nt < 4; ++nt) {
                short8 bv = *(const short8*)&vt[(nt * 16 + l16) * 72 + ks * 32 + quad * 8];
                accv[nt] = __builtin_amdgcn_mfma_f32_16x16x32_bf16(aw, bv, accv[nt], 0, 0, 0);
            }
        }
    }
    dsum += __shfl_xor(dsum, 16);
    dsum += __shfl_xor(dsum, 32);
    __syncthreads();
    float* red = (float*)(smem + 5760);
    float* dred = red + 2048;
    if (quad < 2) {
        #pragma unroll
        for (int nt = 0; nt < 4; ++nt)
            #pragma unroll
            for (int r = 0; r < 4; ++r)
                red[widx * 512 + (quad * 4 + r) * 64 + nt * 16 + l16] = accv[nt][r];
    }
    if (quad == 0 && l16 < 8) dred[widx * 8 + l16] = dsum;
    __syncthreads();
    for (int e = tid; e < 512; e += 256)
        atomicAdd(numer + (size_t)b * 512 + e, red[e] + red[512 + e] + red[1024 + e] + red[1536 + e]);
    if (tid < 8)
        atomicAdd(denom + b * 8 + tid, dred[tid] + dred[8 + tid] + dred[16 + tid] + dred[24 + tid]);
}

// ---------------- GRU + MLP + next q' + zero other numer ----------------
__global__ __launch_bounds__(256) void gru_q_kernel(
    const float* __restrict__ numerX, const float* __restrict__ denom,
    const float* __restrict__ slotsIn,
    const float* __restrict__ vwT, const float* __restrict__ wihT, const float* __restrict__ whhT,
    const float* __restrict__ w1T, const float* __restrict__ w2T,
    const float* __restrict__ bih, const float* __restrict__ bhh,
    const float* __restrict__ nrw, const float* __restrict__ nrb,
    const float* __restrict__ b2,
    const float* __restrict__ qwT, const float* __restrict__ k_w,
    const float* __restrict__ nsw, const float* __restrict__ nsb,
    float* __restrict__ slotsOut, unsigned short* __restrict__ qb,
    float* __restrict__ zbuf)
{
    const int tid = threadIdx.x, lane = tid & 63;
    const int row = blockIdx.x * 4 + (tid >> 6);
    float nx = numerX[row * 64 + lane];
    float xp = 0.f;
    #pragma unroll 8
    for (int i = 0; i < 64; ++i) xp = fmaf(bcastlane(nx, i), vwT[i * 64 + lane], xp);
    float x = xp / denom[row];
    float h = slotsIn[row * 64 + lane];
    float air = 0, aiz = 0, ain = 0, ahr = 0, ahz = 0, ahn = 0;
    #pragma unroll 8
    for (int i = 0; i < 64; ++i) {
        float xi = bcastlane(x, i), hi = bcastlane(h, i);
        const float* wi = wihT + i * 192;
        const float* wh = whhT + i * 192;
        air = fmaf(xi, wi[lane], air);
        aiz = fmaf(xi, wi[64 + lane], aiz);
        ain = fmaf(xi, wi[128 + lane], ain);
        ahr = fmaf(hi, wh[lane], ahr);
        ahz = fmaf(hi, wh[64 + lane], ahz);
        ahn = fmaf(hi, wh[128 + lane], ahn);
    }
    air += bih[lane]; aiz += bih[64 + lane]; ain += bih[128 + lane];
    ahr += bhh[lane]; ahz += bhh[64 + lane]; ahn += bhh[128 + lane];
    float r = 1.f / (1.f + __expf(-(air + ahr)));
    float z = 1.f / (1.f + __expf(-(aiz + ahz)));
    float n = tanhf(ain + r * ahn);
    float hn = (1.f - z) * n + z * h;
    float m = warp_red_sum(hn) * (1.0f / 64.0f);
    float dx = hn - m;
    float var = warp_red_sum(dx * dx) * (1.0f / 64.0f);
    float u = dx * rsqrtf(var + 1e-5f) * nrw[lane] + nrb[lane];
    float o0 = 0.f, o1 = 0.f;
    #pragma unroll 8
    for (int i = 0; i < 64; ++i) {
        float ui = bcastlane(u, i);
        const float* w1r = w1T + i * 128;
        o0 = fmaf(ui, w1r[lane], o0);
        o1 = fmaf(ui, w1r[64 + lane], o1);
    }
    o0 = fmaxf(o0, 0.f); o1 = fmaxf(o1, 0.f);
    float y = 0.f;
    #pragma unroll 8
    for (int j = 0; j < 64; ++j) y = fmaf(bcastlane(o0, j), w2T[j * 64 + lane], y);
    #pragma unroll 8
    for (int j = 0; j < 64; ++j) y = fmaf(bcastlane(o1, j), w2T[(64 + j) * 64 + lane], y);
    y += b2[lane];
    float out = hn + y;
    slotsOut[row * 64 + lane] = out;
    // next-step q' = LN_ns(out)·Wq^T·Wk·0.125
    float m2 = warp_red_sum(out) * (1.0f / 64.0f);
    float dx2 = out - m2;
    float var2 = warp_red_sum(dx2 * dx2) * (1.0f / 64.0f);
    float u2 = dx2 * rsqrtf(var2 + 1e-5f) * nsw[lane] + nsb[lane];
    float q = 0.f;
    #pragma unroll 8
    for (int i = 0; i < 64; ++i) q = fmaf(bcastlane(u2, i), qwT[i * 64 + lane], q);
    float qp = 0.f;
    #pragma unroll 8
    for (int o = 0; o < 64; ++o) qp = fmaf(bcastlane(q, o), k_w[o * 64 + lane], qp);
    qb[row * 64 + lane] = bfu(qp * 0.125f);
    // zero the other numer/denom buffer
    int g = blockIdx.x * 256 + tid;
    for (int j = g; j < 66560; j += 65536) zbuf[j] = 0.f;
}

// ---------------- final renorm of w output ----------------
__global__ __launch_bounds__(256) void renorm_kernel(float* __restrict__ wout,
                                                     const float* __restrict__ denom)
{
    const size_t i4 = (size_t)blockIdx.x * blockDim.x + threadIdx.x;
    const size_t b = i4 >> 13;
    const int half = (int)(i4 & 1);
    float4 v = reinterpret_cast<float4*>(wout)[i4];
    const float4 dv = reinterpret_cast<const float4*>(denom)[b * 2 + half];
    v.x /= dv.x; v.y /= dv.y; v.z /= dv.z; v.w /= dv.w;
    reinterpret_cast<float4*>(wout)[i4] = v;
}

extern "C" void kernel_launch(void* const* d_in, const int* in_sizes, int n_in,
                              void* d_out, int out_size, void* d_ws, size_t ws_size,
                              hipStream_t stream)
{
    const float* inputs  = (const float*)d_in[0];
    const float* eps_n   = (const float*)d_in[1];
    const float* mu      = (const float*)d_in[2];
    const float* lv      = (const float*)d_in[3];
    const float* k_w     = (const float*)d_in[4];
    const float* v_w     = (const float*)d_in[5];
    const float* q_w     = (const float*)d_in[6];
    const float* ni_w    = (const float*)d_in[7];
    const float* ni_b    = (const float*)d_in[8];
    const float* ns_w    = (const float*)d_in[9];
    const float* ns_b    = (const float*)d_in[10];
    const float* nr_w    = (const float*)d_in[11];
    const float* nr_b    = (const float*)d_in[12];
    const float* gru_wih = (const float*)d_in[13];
    const float* gru_whh = (const float*)d_in[14];
    const float* gru_bih = (const float*)d_in[15];
    const float* gru_bhh = (const float*)d_in[16];
    const float* mlp_w1  = (const float*)d_in[17];
    const float* mlp_w2  = (const float*)d_in[18];
    const float* mlp_b2  = (const float*)d_in[19];

    char* wsb = (char*)d_ws;
    unsigned short* xb  = (unsigned short*)wsb;                    // [B][N][64] bf16 (LN'd X)
    unsigned short* xbt = (unsigned short*)(wsb + 67108864);       // [B][64][N] bf16 (X^T)
    float* f      = (float*)(wsb + 134217728);
    float* slotsA = f;                                   // 65536
    float* slotsB = f + 65536;                           // 65536
    unsigned short* qb = (unsigned short*)(f + 131072);  // 65536 bf16 (q')
    float* numer0 = f + 163840;                          // 65536
    float* denom0 = f + 229376;                          // 1024
    float* numer1 = f + 230400;                          // 65536
    float* denom1 = f + 295936;                          // 1024
    float* vwT    = f + 296960;                          // 4096
    float* qwT    = f + 301056;                          // 4096
    float* wihT   = f + 305152;                          // 12288
    float* whhT   = f + 317440;                          // 12288
    float* w1T    = f + 329728;                          // 8192
    float* w2T    = f + 337920;                          // 8192

    float* out_slots = (float*)d_out;
    float* out_w     = out_slots + 65536;

    prep_kernel<<<64, 256, 0, stream>>>(v_w, q_w, gru_wih, gru_whh, mlp_w1, mlp_w2,
                                        vwT, qwT, wihT, whhT, w1T, w2T);
    init_q_kernel<<<256, 256, 0, stream>>>(eps_n, mu, lv, qwT, k_w, ns_w, ns_b,
                                           slotsA, qb, numer0);
    phase_a_ln<<<4096, 256, 0, stream>>>(inputs, ni_w, ni_b, xb, xbt);

    float* cur = slotsA;
    float* numers[2] = {numer0, numer1};
    float* denoms[2] = {denom0, denom1};
    for (int step = 0; step < 4; ++step) {
        int pb = step & 1;
        attn_mfma<<<dim3(8, 128), 256, 0, stream>>>((const __hip_bfloat16*)xb, xbt, qb,
                                                    numers[pb], denoms[pb],
                                                    step == 3 ? out_w : nullptr);
        float* nxt = (step == 3) ? out_slots : ((step & 1) ? slotsA : slotsB);
        gru_q_kernel<<<256, 256, 0, stream>>>(numers[pb], denoms[pb], cur,
                                              vwT, wihT, whhT, w1T, w2T,
                                              gru_bih, gru_bhh, nr_w, nr_b, mlp_b2,
                                              qwT, k_w, ns_w, ns_b,
                                              nxt, qb, numers[1 - pb]);
        cur = nxt;
    }
    renorm_kernel<<<4096, 256, 0, stream>>>(out_w, denom1);
}

// Round 6
// 448.124 us; speedup vs baseline: 1.0178x; 1.0178x over previous
//
#include <hip/hip_runtime.h>
#include <hip/hip_bf16.h>

#define BB 128
#define NN 4096
#define DD 64
#define SS 8
#define HH 128

typedef __attribute__((ext_vector_type(8))) short short8;
typedef __attribute__((ext_vector_type(4))) float f32x4;

__device__ __forceinline__ float warp_red_sum(float v) {
    #pragma unroll
    for (int off = 32; off; off >>= 1) v += __shfl_xor(v, off);
    return v;
}

__device__ __forceinline__ float bcastlane(float v, int l) {
    return __int_as_float(__builtin_amdgcn_readlane(__float_as_int(v), l));
}

__device__ __forceinline__ unsigned short bfu(float f) {
    __hip_bfloat16 h = __float2bfloat16(f);
    return *(unsigned short*)&h;
}

__device__ __forceinline__ unsigned pk2(float a, float b) {
    return (unsigned)bfu(a) | ((unsigned)bfu(b) << 16);
}

// ---------------- prep: small weight transposes ----------------
__global__ __launch_bounds__(256) void prep_kernel(
    const float* __restrict__ v_w, const float* __restrict__ q_w,
    const float* __restrict__ wih, const float* __restrict__ whh,
    const float* __restrict__ w1, const float* __restrict__ w2,
    float* __restrict__ vwT, float* __restrict__ qwT,
    float* __restrict__ wihT, float* __restrict__ whhT,
    float* __restrict__ w1T, float* __restrict__ w2T)
{
    int i0 = blockIdx.x * blockDim.x + threadIdx.x;
    int nthr = gridDim.x * blockDim.x;
    for (int t = i0; t < 4096; t += nthr) {
        int i = t >> 6, o = t & 63;
        vwT[t] = v_w[o * 64 + i];          // vwT[i][o]
        qwT[t] = q_w[o * 64 + i];          // qwT[i][o]
    }
    for (int t = i0; t < 12288; t += nthr) {
        int r = t / 192, c = t % 192;
        wihT[t] = wih[c * 64 + r];
        whhT[t] = whh[c * 64 + r];
    }
    for (int t = i0; t < 8192; t += nthr) {
        int r = t >> 7, c = t & 127;
        w1T[t] = w1[c * 64 + r];
    }
    for (int t = i0; t < 8192; t += nthr) {
        int r = t >> 6, c = t & 63;
        w2T[t] = w2[c * 128 + r];
    }
}

// ---------------- init: slots + q' (q·Wk/8) + zero numer0 ----------------
__global__ __launch_bounds__(256) void init_q_kernel(
    const float* __restrict__ eps, const float* __restrict__ mu,
    const float* __restrict__ lv, const float* __restrict__ qwT,
    const float* __restrict__ k_w,
    const float* __restrict__ nsw, const float* __restrict__ nsb,
    float* __restrict__ slots, unsigned short* __restrict__ qb,
    float* __restrict__ zbuf)
{
    const int tid = threadIdx.x, lane = tid & 63;
    const int row = blockIdx.x * 4 + (tid >> 6);     // 1024 rows = B*S
    const int idx = row * 64 + lane;
    float s0 = mu[lane] + __expf(0.5f * lv[lane]) * eps[idx];
    slots[idx] = s0;
    float m = warp_red_sum(s0) * (1.0f / 64.0f);
    float dx = s0 - m;
    float var = warp_red_sum(dx * dx) * (1.0f / 64.0f);
    float xln = dx * rsqrtf(var + 1e-5f) * nsw[lane] + nsb[lane];
    float q = 0.f;
    #pragma unroll 8
    for (int i = 0; i < 64; ++i) q = fmaf(bcastlane(xln, i), qwT[i * 64 + lane], q);
    float qp = 0.f;
    #pragma unroll 8
    for (int o = 0; o < 64; ++o) qp = fmaf(bcastlane(q, o), k_w[o * 64 + lane], qp);
    qb[idx] = bfu(qp * 0.125f);
    int g = blockIdx.x * 256 + tid;
    for (int j = g; j < 66560; j += 65536) zbuf[j] = 0.f;
}

// ---------------- phase A: streaming LN -> X bf16 [tok][d] and X^T bf16 [b][d][tok] ----------------
// xt transpose uses XOR column swizzle (8-token chunks, s(d) = (d>>2)&7) to break
// the dq*16 ≡ {0,16} bank pattern (was 8-way conflicts).
__global__ __launch_bounds__(256) void phase_a_ln(
    const float* __restrict__ inp, const float* __restrict__ niw, const float* __restrict__ nib,
    unsigned short* __restrict__ xb, unsigned short* __restrict__ xbt)
{
    __shared__ unsigned short xt[64 * 136];
    const int tid = threadIdx.x, lane = tid & 63, widx = tid >> 6;
    const int tg = lane >> 4, dq = lane & 15;
    const float4 wni = *(const float4*)&niw[dq * 4];
    const float4 bni = *(const float4*)&nib[dq * 4];
    const int tok0 = blockIdx.x * 128;
    const int sw = dq & 7;
    #pragma unroll
    for (int it = 0; it < 8; ++it) {
        const int m = widx * 32 + it * 4 + tg;
        float4 x = *(const float4*)&inp[(size_t)(tok0 + m) * 64 + dq * 4];
        float s1 = x.x + x.y + x.z + x.w;
        float s2 = fmaf(x.x, x.x, fmaf(x.y, x.y, fmaf(x.z, x.z, x.w * x.w)));
        #pragma unroll
        for (int o = 1; o < 16; o <<= 1) { s1 += __shfl_xor(s1, o); s2 += __shfl_xor(s2, o); }
        float mean = s1 * (1.0f / 64.0f);
        float var = s2 * (1.0f / 64.0f) - mean * mean;
        float rstd = rsqrtf(var + 1e-5f);
        float y0 = (x.x - mean) * rstd * wni.x + bni.x;
        float y1 = (x.y - mean) * rstd * wni.y + bni.y;
        float y2 = (x.z - mean) * rstd * wni.z + bni.z;
        float y3 = (x.w - mean) * rstd * wni.w + bni.w;
        uint2 p; p.x = pk2(y0, y1); p.y = pk2(y2, y3);
        *(uint2*)&xb[(size_t)(tok0 + m) * 64 + dq * 4] = p;
        const int col = ((((m >> 3) ^ sw) << 3) | (m & 7));
        xt[(dq * 4 + 0) * 136 + col] = bfu(y0);
        xt[(dq * 4 + 1) * 136 + col] = bfu(y1);
        xt[(dq * 4 + 2) * 136 + col] = bfu(y2);
        xt[(dq * 4 + 3) * 136 + col] = bfu(y3);
    }
    __syncthreads();
    const int b = blockIdx.x >> 5, tin = (blockIdx.x & 31) * 128;
    const int d = tid >> 2, q4 = tid & 3;
    const int sr = (d >> 2) & 7;
    #pragma unroll
    for (int c = 0; c < 4; ++c) {
        const int cc = q4 * 4 + c;
        uint4 o = *(uint4*)&xt[d * 136 + ((cc ^ sr) << 3)];
        *(uint4*)&xbt[((size_t)b * 64 + d) * 4096 + tin + cc * 8] = o;
    }
}

// ---------------- attention via MFMA: q'·X^T -> softmax -> w^T·X (numerX) ----------------
// QK orientation: A = q' (M=slots), B = X rows (N=tokens). D: col=token, row=slot.
// Softmax over slots = 3 in-lane adds + 1 shfl_xor(16) + rcp.
__global__ __launch_bounds__(256) void attn_mfma(
    const __hip_bfloat16* __restrict__ xb, const unsigned short* __restrict__ xbt,
    const unsigned short* __restrict__ qb,
    float* __restrict__ numer, float* __restrict__ denom, float* __restrict__ wout)
{
    __shared__ unsigned short smem[24192];
    unsigned short* Qs = smem;                          // [16][72]
    const int tid = threadIdx.x, lane = tid & 63, widx = tid >> 6;
    unsigned short* wls = smem + 1152 + widx * 1152;    // [16][72]
    unsigned short* vt  = smem + 5760 + widx * 4608;    // [64][72]
    const int b = blockIdx.y;

    for (int t = tid; t < 1024; t += 256) {
        int s = t >> 6, dd = t & 63;
        Qs[s * 72 + dd] = (s < 8) ? qb[b * 512 + t] : (unsigned short)0;
    }
    for (int t = lane; t < 576; t += 64) wls[576 + t] = 0;
    __syncthreads();

    const int quad = lane >> 4, l16 = lane & 15;
    short8 aq0 = *(const short8*)&Qs[l16 * 72 + quad * 8];       // A-frag: m=slot(l16), k=quad*8+j
    short8 aq1 = *(const short8*)&Qs[l16 * 72 + 32 + quad * 8];

    f32x4 accv[4];
    #pragma unroll
    for (int nt = 0; nt < 4; ++nt) accv[nt] = (f32x4){0.f, 0.f, 0.f, 0.f};
    float dacc[4] = {0.f, 0.f, 0.f, 0.f};

    const int twave0 = blockIdx.x * 512 + widx * 128;
    const int vd = lane >> 3, vc = (lane & 7) * 8;
    #pragma unroll
    for (int iter = 0; iter < 2; ++iter) {
        const int t0 = twave0 + iter * 64;
        uint4 vld[8];
        #pragma unroll
        for (int i = 0; i < 8; ++i)
            vld[i] = *(const uint4*)&xbt[((size_t)b * 64 + i * 8 + vd) * 4096 + t0 + vc];

        #pragma unroll
        for (int t4 = 0; t4 < 4; ++t4) {
            const int tok = t0 + t4 * 16 + l16;
            const size_t xrow = ((size_t)b * NN + tok) * 64;
            short8 bk0 = *(const short8*)&xb[xrow + quad * 8];   // B-frag: n=token(l16), k=quad*8+j
            short8 bk1 = *(const short8*)&xb[xrow + 32 + quad * 8];
            f32x4 lg = (f32x4){0.f, 0.f, 0.f, 0.f};
            lg = __builtin_amdgcn_mfma_f32_16x16x32_bf16(aq0, bk0, lg, 0, 0, 0);
            lg = __builtin_amdgcn_mfma_f32_16x16x32_bf16(aq1, bk1, lg, 0, 0, 0);
            // lane holds logits for token=l16-col, slots quad*4+r (quads 2,3 = pad, discarded)
            float e[4];
            #pragma unroll
            for (int r = 0; r < 4; ++r) e[r] = __expf(lg[r]);
            float s4 = (e[0] + e[1]) + (e[2] + e[3]);
            float stot = s4 + __shfl_xor(s4, 16);
            float rs = __builtin_amdgcn_rcpf(stot);
            float wv[4];
            #pragma unroll
            for (int r = 0; r < 4; ++r) { wv[r] = fmaf(e[r], rs, 1e-8f); dacc[r] += wv[r]; }
            if (quad < 2) {
                #pragma unroll
                for (int r = 0; r < 4; ++r)
                    wls[(quad * 4 + r) * 72 + t4 * 16 + l16] = bfu(wv[r]);
                if (wout)
                    *(float4*)&wout[((size_t)b * NN + tok) * 8 + quad * 4] =
                        make_float4(wv[0], wv[1], wv[2], wv[3]);
            }
        }
        #pragma unroll
        for (int i = 0; i < 8; ++i)
            *(uint4*)&vt[(i * 8 + vd) * 72 + vc] = vld[i];
        #pragma unroll
        for (int ks = 0; ks < 2; ++ks) {
            short8 aw = *(const short8*)&wls[l16 * 72 + ks * 32 + quad * 8];
            #pragma unroll
            for (int nt = 0; nt < 4; ++nt) {
                short8 bv = *(const short8*)&vt[(nt * 16 + l16) * 72 + ks * 32 + quad * 8];
                accv[nt] = __builtin_amdgcn_mfma_f32_16x16x32_bf16(aw, bv, accv[nt], 0, 0, 0);
            }
        }
    }
    // denom: reduce dacc over the 16 tokens in l16 (per slot = quad*4+r)
    #pragma unroll
    for (int r = 0; r < 4; ++r) {
        dacc[r] += __shfl_xor(dacc[r], 1);
        dacc[r] += __shfl_xor(dacc[r], 2);
        dacc[r] += __shfl_xor(dacc[r], 4);
        dacc[r] += __shfl_xor(dacc[r], 8);
    }
    __syncthreads();
    float* red = (float*)(smem + 5760);
    float* dred = red + 2048;
    if (quad < 2) {
        #pragma unroll
        for (int nt = 0; nt < 4; ++nt)
            #pragma unroll
            for (int r = 0; r < 4; ++r)
                red[widx * 512 + (quad * 4 + r) * 64 + nt * 16 + l16] = accv[nt][r];
        if (l16 == 0) {
            #pragma unroll
            for (int r = 0; r < 4; ++r) dred[widx * 8 + quad * 4 + r] = dacc[r];
        }
    }
    __syncthreads();
    for (int e = tid; e < 512; e += 256)
        atomicAdd(numer + (size_t)b * 512 + e, red[e] + red[512 + e] + red[1024 + e] + red[1536 + e]);
    if (tid < 8)
        atomicAdd(denom + b * 8 + tid, dred[tid] + dred[8 + tid] + dred[16 + tid] + dred[24 + tid]);
}

// ---------------- GRU + MLP + next q' + zero other numer ----------------
__global__ __launch_bounds__(256) void gru_q_kernel(
    const float* __restrict__ numerX, const float* __restrict__ denom,
    const float* __restrict__ slotsIn,
    const float* __restrict__ vwT, const float* __restrict__ wihT, const float* __restrict__ whhT,
    const float* __restrict__ w1T, const float* __restrict__ w2T,
    const float* __restrict__ bih, const float* __restrict__ bhh,
    const float* __restrict__ nrw, const float* __restrict__ nrb,
    const float* __restrict__ b2,
    const float* __restrict__ qwT, const float* __restrict__ k_w,
    const float* __restrict__ nsw, const float* __restrict__ nsb,
    float* __restrict__ slotsOut, unsigned short* __restrict__ qb,
    float* __restrict__ zbuf)
{
    const int tid = threadIdx.x, lane = tid & 63;
    const int row = blockIdx.x * 4 + (tid >> 6);
    float nx = numerX[row * 64 + lane];
    float xp = 0.f;
    #pragma unroll 8
    for (int i = 0; i < 64; ++i) xp = fmaf(bcastlane(nx, i), vwT[i * 64 + lane], xp);
    float x = xp / denom[row];
    float h = slotsIn[row * 64 + lane];
    float air = 0, aiz = 0, ain = 0, ahr = 0, ahz = 0, ahn = 0;
    #pragma unroll 8
    for (int i = 0; i < 64; ++i) {
        float xi = bcastlane(x, i), hi = bcastlane(h, i);
        const float* wi = wihT + i * 192;
        const float* wh = whhT + i * 192;
        air = fmaf(xi, wi[lane], air);
        aiz = fmaf(xi, wi[64 + lane], aiz);
        ain = fmaf(xi, wi[128 + lane], ain);
        ahr = fmaf(hi, wh[lane], ahr);
        ahz = fmaf(hi, wh[64 + lane], ahz);
        ahn = fmaf(hi, wh[128 + lane], ahn);
    }
    air += bih[lane]; aiz += bih[64 + lane]; ain += bih[128 + lane];
    ahr += bhh[lane]; ahz += bhh[64 + lane]; ahn += bhh[128 + lane];
    float r = 1.f / (1.f + __expf(-(air + ahr)));
    float z = 1.f / (1.f + __expf(-(aiz + ahz)));
    float n = tanhf(ain + r * ahn);
    float hn = (1.f - z) * n + z * h;
    float m = warp_red_sum(hn) * (1.0f / 64.0f);
    float dx = hn - m;
    float var = warp_red_sum(dx * dx) * (1.0f / 64.0f);
    float u = dx * rsqrtf(var + 1e-5f) * nrw[lane] + nrb[lane];
    float o0 = 0.f, o1 = 0.f;
    #pragma unroll 8
    for (int i = 0; i < 64; ++i) {
        float ui = bcastlane(u, i);
        const float* w1r = w1T + i * 128;
        o0 = fmaf(ui, w1r[lane], o0);
        o1 = fmaf(ui, w1r[64 + lane], o1);
    }
    o0 = fmaxf(o0, 0.f); o1 = fmaxf(o1, 0.f);
    float y = 0.f;
    #pragma unroll 8
    for (int j = 0; j < 64; ++j) y = fmaf(bcastlane(o0, j), w2T[j * 64 + lane], y);
    #pragma unroll 8
    for (int j = 0; j < 64; ++j) y = fmaf(bcastlane(o1, j), w2T[(64 + j) * 64 + lane], y);
    y += b2[lane];
    float out = hn + y;
    slotsOut[row * 64 + lane] = out;
    float m2 = warp_red_sum(out) * (1.0f / 64.0f);
    float dx2 = out - m2;
    float var2 = warp_red_sum(dx2 * dx2) * (1.0f / 64.0f);
    float u2 = dx2 * rsqrtf(var2 + 1e-5f) * nsw[lane] + nsb[lane];
    float q = 0.f;
    #pragma unroll 8
    for (int i = 0; i < 64; ++i) q = fmaf(bcastlane(u2, i), qwT[i * 64 + lane], q);
    float qp = 0.f;
    #pragma unroll 8
    for (int o = 0; o < 64; ++o) qp = fmaf(bcastlane(q, o), k_w[o * 64 + lane], qp);
    qb[row * 64 + lane] = bfu(qp * 0.125f);
    int g = blockIdx.x * 256 + tid;
    for (int j = g; j < 66560; j += 65536) zbuf[j] = 0.f;
}

// ---------------- final renorm of w output ----------------
__global__ __launch_bounds__(256) void renorm_kernel(float* __restrict__ wout,
                                                     const float* __restrict__ denom)
{
    const size_t i4 = (size_t)blockIdx.x * blockDim.x + threadIdx.x;
    const size_t b = i4 >> 13;
    const int half = (int)(i4 & 1);
    float4 v = reinterpret_cast<float4*>(wout)[i4];
    const float4 dv = reinterpret_cast<const float4*>(denom)[b * 2 + half];
    v.x /= dv.x; v.y /= dv.y; v.z /= dv.z; v.w /= dv.w;
    reinterpret_cast<float4*>(wout)[i4] = v;
}

extern "C" void kernel_launch(void* const* d_in, const int* in_sizes, int n_in,
                              void* d_out, int out_size, void* d_ws, size_t ws_size,
                              hipStream_t stream)
{
    const float* inputs  = (const float*)d_in[0];
    const float* eps_n   = (const float*)d_in[1];
    const float* mu      = (const float*)d_in[2];
    const float* lv      = (const float*)d_in[3];
    const float* k_w     = (const float*)d_in[4];
    const float* v_w     = (const float*)d_in[5];
    const float* q_w     = (const float*)d_in[6];
    const float* ni_w    = (const float*)d_in[7];
    const float* ni_b    = (const float*)d_in[8];
    const float* ns_w    = (const float*)d_in[9];
    const float* ns_b    = (const float*)d_in[10];
    const float* nr_w    = (const float*)d_in[11];
    const float* nr_b    = (const float*)d_in[12];
    const float* gru_wih = (const float*)d_in[13];
    const float* gru_whh = (const float*)d_in[14];
    const float* gru_bih = (const float*)d_in[15];
    const float* gru_bhh = (const float*)d_in[16];
    const float* mlp_w1  = (const float*)d_in[17];
    const float* mlp_w2  = (const float*)d_in[18];
    const float* mlp_b2  = (const float*)d_in[19];

    char* wsb = (char*)d_ws;
    unsigned short* xb  = (unsigned short*)wsb;                    // [B][N][64] bf16 (LN'd X)
    unsigned short* xbt = (unsigned short*)(wsb + 67108864);       // [B][64][N] bf16 (X^T)
    float* f      = (float*)(wsb + 134217728);
    float* slotsA = f;                                   // 65536
    float* slotsB = f + 65536;                           // 65536
    unsigned short* qb = (unsigned short*)(f + 131072);  // 65536 bf16 (q')
    float* numer0 = f + 163840;                          // 65536
    float* denom0 = f + 229376;                          // 1024
    float* numer1 = f + 230400;                          // 65536
    float* denom1 = f + 295936;                          // 1024
    float* vwT    = f + 296960;                          // 4096
    float* qwT    = f + 301056;                          // 4096
    float* wihT   = f + 305152;                          // 12288
    float* whhT   = f + 317440;                          // 12288
    float* w1T    = f + 329728;                          // 8192
    float* w2T    = f + 337920;                          // 8192

    float* out_slots = (float*)d_out;
    float* out_w     = out_slots + 65536;

    prep_kernel<<<64, 256, 0, stream>>>(v_w, q_w, gru_wih, gru_whh, mlp_w1, mlp_w2,
                                        vwT, qwT, wihT, whhT, w1T, w2T);
    init_q_kernel<<<256, 256, 0, stream>>>(eps_n, mu, lv, qwT, k_w, ns_w, ns_b,
                                           slotsA, qb, numer0);
    phase_a_ln<<<4096, 256, 0, stream>>>(inputs, ni_w, ni_b, xb, xbt);

    float* cur = slotsA;
    float* numers[2] = {numer0, numer1};
    float* denoms[2] = {denom0, denom1};
    for (int step = 0; step < 4; ++step) {
        int pb = step & 1;
        attn_mfma<<<dim3(8, 128), 256, 0, stream>>>((const __hip_bfloat16*)xb, xbt, qb,
                                                    numers[pb], denoms[pb],
                                                    step == 3 ? out_w : nullptr);
        float* nxt = (step == 3) ? out_slots : ((step & 1) ? slotsA : slotsB);
        gru_q_kernel<<<256, 256, 0, stream>>>(numers[pb], denoms[pb], cur,
                                              vwT, wihT, whhT, w1T, w2T,
                                              gru_bih, gru_bhh, nr_w, nr_b, mlp_b2,
                                              qwT, k_w, ns_w, ns_b,
                                              nxt, qb, numers[1 - pb]);
        cur = nxt;
    }
    renorm_kernel<<<4096, 256, 0, stream>>>(out_w, denom1);
}

// Round 7
// 446.159 us; speedup vs baseline: 1.0223x; 1.0044x over previous
//
#include <hip/hip_runtime.h>
#include <hip/hip_bf16.h>

#define BB 128
#define NN 4096
#define DD 64
#define SS 8
#define HH 128

typedef __attribute__((ext_vector_type(8))) short short8;
typedef __attribute__((ext_vector_type(4))) float f32x4;

__device__ __forceinline__ float warp_red_sum(float v) {
    #pragma unroll
    for (int off = 32; off; off >>= 1) v += __shfl_xor(v, off);
    return v;
}

__device__ __forceinline__ float bcastlane(float v, int l) {
    return __int_as_float(__builtin_amdgcn_readlane(__float_as_int(v), l));
}

__device__ __forceinline__ unsigned short bfu(float f) {
    __hip_bfloat16 h = __float2bfloat16(f);
    return *(unsigned short*)&h;
}

__device__ __forceinline__ unsigned pk2(float a, float b) {
    return (unsigned)bfu(a) | ((unsigned)bfu(b) << 16);
}

// ---------------- prep: small weight transposes ----------------
__global__ __launch_bounds__(256) void prep_kernel(
    const float* __restrict__ v_w, const float* __restrict__ q_w,
    const float* __restrict__ wih, const float* __restrict__ whh,
    const float* __restrict__ w1, const float* __restrict__ w2,
    float* __restrict__ vwT, float* __restrict__ qwT,
    float* __restrict__ wihT, float* __restrict__ whhT,
    float* __restrict__ w1T, float* __restrict__ w2T)
{
    int i0 = blockIdx.x * blockDim.x + threadIdx.x;
    int nthr = gridDim.x * blockDim.x;
    for (int t = i0; t < 4096; t += nthr) {
        int i = t >> 6, o = t & 63;
        vwT[t] = v_w[o * 64 + i];          // vwT[i][o]
        qwT[t] = q_w[o * 64 + i];          // qwT[i][o]
    }
    for (int t = i0; t < 12288; t += nthr) {
        int r = t / 192, c = t % 192;
        wihT[t] = wih[c * 64 + r];
        whhT[t] = whh[c * 64 + r];
    }
    for (int t = i0; t < 8192; t += nthr) {
        int r = t >> 7, c = t & 127;
        w1T[t] = w1[c * 64 + r];
    }
    for (int t = i0; t < 8192; t += nthr) {
        int r = t >> 6, c = t & 63;
        w2T[t] = w2[c * 128 + r];
    }
}

// ---------------- init: slots + q' (q·Wk/8) + zero numer0 ----------------
__global__ __launch_bounds__(256) void init_q_kernel(
    const float* __restrict__ eps, const float* __restrict__ mu,
    const float* __restrict__ lv, const float* __restrict__ qwT,
    const float* __restrict__ k_w,
    const float* __restrict__ nsw, const float* __restrict__ nsb,
    float* __restrict__ slots, unsigned short* __restrict__ qb,
    float* __restrict__ zbuf)
{
    const int tid = threadIdx.x, lane = tid & 63;
    const int row = blockIdx.x * 4 + (tid >> 6);     // 1024 rows = B*S
    const int idx = row * 64 + lane;
    float s0 = mu[lane] + __expf(0.5f * lv[lane]) * eps[idx];
    slots[idx] = s0;
    float m = warp_red_sum(s0) * (1.0f / 64.0f);
    float dx = s0 - m;
    float var = warp_red_sum(dx * dx) * (1.0f / 64.0f);
    float xln = dx * rsqrtf(var + 1e-5f) * nsw[lane] + nsb[lane];
    float q = 0.f;
    #pragma unroll 8
    for (int i = 0; i < 64; ++i) q = fmaf(bcastlane(xln, i), qwT[i * 64 + lane], q);
    float qp = 0.f;
    #pragma unroll 8
    for (int o = 0; o < 64; ++o) qp = fmaf(bcastlane(q, o), k_w[o * 64 + lane], qp);
    qb[idx] = bfu(qp * 0.125f);
    int g = blockIdx.x * 256 + tid;
    for (int j = g; j < 66560; j += 65536) zbuf[j] = 0.f;
}

// ---------------- phase A: streaming LN -> X bf16 [tok][d] and X^T bf16 [b][d][tok] ----------------
// Lane owns 8 contiguous d's of one token: float4 x2 load, 6 shfls / 8 tokens,
// uint4 (16B) coalesced xb store. xt transpose swizzled at 4-bit granularity
// (sw=(d>>2)&15) so scalar writes are <=2-way (free).
__global__ __launch_bounds__(256) void phase_a_ln(
    const float* __restrict__ inp, const float* __restrict__ niw, const float* __restrict__ nib,
    unsigned short* __restrict__ xb, unsigned short* __restrict__ xbt)
{
    __shared__ unsigned short xt[64 * 136];
    const int tid = threadIdx.x, lane = tid & 63, widx = tid >> 6;
    const int t8 = lane >> 3, d8 = lane & 7;
    const float4 wn0 = *(const float4*)&niw[d8 * 8];
    const float4 wn1 = *(const float4*)&niw[d8 * 8 + 4];
    const float4 bn0 = *(const float4*)&nib[d8 * 8];
    const float4 bn1 = *(const float4*)&nib[d8 * 8 + 4];
    const int tok0 = blockIdx.x * 128;
    #pragma unroll
    for (int it = 0; it < 4; ++it) {
        const int m = widx * 32 + it * 8 + t8;
        const float* rowp = inp + (size_t)(tok0 + m) * 64 + d8 * 8;
        float4 a = *(const float4*)rowp;
        float4 c = *(const float4*)(rowp + 4);
        float s1 = (a.x + a.y + a.z + a.w) + (c.x + c.y + c.z + c.w);
        float s2 = fmaf(a.x, a.x, fmaf(a.y, a.y, fmaf(a.z, a.z, a.w * a.w)));
        s2 = fmaf(c.x, c.x, fmaf(c.y, c.y, fmaf(c.z, c.z, fmaf(c.w, c.w, s2))));
        #pragma unroll
        for (int o = 1; o < 8; o <<= 1) { s1 += __shfl_xor(s1, o); s2 += __shfl_xor(s2, o); }
        float mean = s1 * (1.0f / 64.0f);
        float var = s2 * (1.0f / 64.0f) - mean * mean;
        float rstd = rsqrtf(var + 1e-5f);
        float y[8];
        y[0] = (a.x - mean) * rstd * wn0.x + bn0.x;
        y[1] = (a.y - mean) * rstd * wn0.y + bn0.y;
        y[2] = (a.z - mean) * rstd * wn0.z + bn0.z;
        y[3] = (a.w - mean) * rstd * wn0.w + bn0.w;
        y[4] = (c.x - mean) * rstd * wn1.x + bn1.x;
        y[5] = (c.y - mean) * rstd * wn1.y + bn1.y;
        y[6] = (c.z - mean) * rstd * wn1.z + bn1.z;
        y[7] = (c.w - mean) * rstd * wn1.w + bn1.w;
        uint4 o4;
        o4.x = pk2(y[0], y[1]); o4.y = pk2(y[2], y[3]);
        o4.z = pk2(y[4], y[5]); o4.w = pk2(y[6], y[7]);
        *(uint4*)&xb[(size_t)(tok0 + m) * 64 + d8 * 8] = o4;
        const int mh = m >> 3, ml = m & 7;
        #pragma unroll
        for (int j = 0; j < 8; ++j) {
            const int d = d8 * 8 + j;
            const int col = (((mh ^ ((d >> 2) & 15)) << 3) | ml);
            xt[d * 136 + col] = bfu(y[j]);
        }
    }
    __syncthreads();
    const int b = blockIdx.x >> 5, tin = (blockIdx.x & 31) * 128;
    const int d = tid >> 2, q4 = tid & 3;
    const int sr = (d >> 2) & 15;
    #pragma unroll
    for (int c = 0; c < 4; ++c) {
        const int cc = q4 * 4 + c;
        uint4 o = *(uint4*)&xt[d * 136 + ((cc ^ sr) << 3)];
        *(uint4*)&xbt[((size_t)b * 64 + d) * 4096 + tin + cc * 8] = o;
    }
}

// ---------------- attention via MFMA: q'·X^T -> softmax -> w^T·X (numerX) ----------------
// QK: A=q' (M=slots), B=X rows. PV: B-frags loaded DIRECTLY from global xbt
// (no LDS staging) -> LDS 11.5 KB -> 8 blocks/CU.
__global__ __launch_bounds__(256) void attn_mfma(
    const __hip_bfloat16* __restrict__ xb, const unsigned short* __restrict__ xbt,
    const unsigned short* __restrict__ qb,
    float* __restrict__ numer, float* __restrict__ denom, float* __restrict__ wout)
{
    __shared__ unsigned short smem[5760];
    unsigned short* Qs = smem;                          // [16][72]
    const int tid = threadIdx.x, lane = tid & 63, widx = tid >> 6;
    unsigned short* wls = smem + 1152 + widx * 1152;    // [16][72] per wave
    const int b = blockIdx.y;

    for (int t = tid; t < 1024; t += 256) {
        int s = t >> 6, dd = t & 63;
        Qs[s * 72 + dd] = (s < 8) ? qb[b * 512 + t] : (unsigned short)0;
    }
    for (int t = lane; t < 576; t += 64) wls[576 + t] = 0;
    __syncthreads();

    const int quad = lane >> 4, l16 = lane & 15;
    short8 aq0 = *(const short8*)&Qs[l16 * 72 + quad * 8];       // A: m=slot(l16), k=quad*8+j
    short8 aq1 = *(const short8*)&Qs[l16 * 72 + 32 + quad * 8];

    f32x4 accv[4];
    #pragma unroll
    for (int nt = 0; nt < 4; ++nt) accv[nt] = (f32x4){0.f, 0.f, 0.f, 0.f};
    float dacc[4] = {0.f, 0.f, 0.f, 0.f};

    const int twave0 = blockIdx.x * 512 + widx * 128;
    #pragma unroll
    for (int iter = 0; iter < 2; ++iter) {
        const int t0 = twave0 + iter * 64;
        // PV B-frags: direct global loads (issued early; same bytes the old LDS path staged)
        short8 bvr[8];
        #pragma unroll
        for (int ks = 0; ks < 2; ++ks)
            #pragma unroll
            for (int nt = 0; nt < 4; ++nt)
                bvr[ks * 4 + nt] = *(const short8*)&xbt[((size_t)b * 64 + nt * 16 + l16) * 4096
                                                        + t0 + ks * 32 + quad * 8];

        #pragma unroll
        for (int t4 = 0; t4 < 4; ++t4) {
            const int tok = t0 + t4 * 16 + l16;
            const size_t xrow = ((size_t)b * NN + tok) * 64;
            short8 bk0 = *(const short8*)&xb[xrow + quad * 8];   // B: n=token(l16), k=quad*8+j
            short8 bk1 = *(const short8*)&xb[xrow + 32 + quad * 8];
            f32x4 lg = (f32x4){0.f, 0.f, 0.f, 0.f};
            lg = __builtin_amdgcn_mfma_f32_16x16x32_bf16(aq0, bk0, lg, 0, 0, 0);
            lg = __builtin_amdgcn_mfma_f32_16x16x32_bf16(aq1, bk1, lg, 0, 0, 0);
            float e[4];
            #pragma unroll
            for (int r = 0; r < 4; ++r) e[r] = __expf(lg[r]);
            float s4 = (e[0] + e[1]) + (e[2] + e[3]);
            float stot = s4 + __shfl_xor(s4, 16);
            float rs = __builtin_amdgcn_rcpf(stot);
            float wv[4];
            #pragma unroll
            for (int r = 0; r < 4; ++r) { wv[r] = fmaf(e[r], rs, 1e-8f); dacc[r] += wv[r]; }
            if (quad < 2) {
                #pragma unroll
                for (int r = 0; r < 4; ++r)
                    wls[(quad * 4 + r) * 72 + t4 * 16 + l16] = bfu(wv[r]);
                if (wout)
                    *(float4*)&wout[((size_t)b * NN + tok) * 8 + quad * 4] =
                        make_float4(wv[0], wv[1], wv[2], wv[3]);
            }
        }
        #pragma unroll
        for (int ks = 0; ks < 2; ++ks) {
            short8 aw = *(const short8*)&wls[l16 * 72 + ks * 32 + quad * 8];
            #pragma unroll
            for (int nt = 0; nt < 4; ++nt)
                accv[nt] = __builtin_amdgcn_mfma_f32_16x16x32_bf16(aw, bvr[ks * 4 + nt],
                                                                   accv[nt], 0, 0, 0);
        }
    }
    // denom: reduce dacc over the 16 tokens in l16 (per slot = quad*4+r)
    #pragma unroll
    for (int r = 0; r < 4; ++r) {
        dacc[r] += __shfl_xor(dacc[r], 1);
        dacc[r] += __shfl_xor(dacc[r], 2);
        dacc[r] += __shfl_xor(dacc[r], 4);
        dacc[r] += __shfl_xor(dacc[r], 8);
    }
    __syncthreads();
    float* red = (float*)smem;           // overlays Qs/wls (done with them)
    float* dred = red + 2048;
    if (quad < 2) {
        #pragma unroll
        for (int nt = 0; nt < 4; ++nt)
            #pragma unroll
            for (int r = 0; r < 4; ++r)
                red[widx * 512 + (quad * 4 + r) * 64 + nt * 16 + l16] = accv[nt][r];
        if (l16 == 0) {
            #pragma unroll
            for (int r = 0; r < 4; ++r) dred[widx * 8 + quad * 4 + r] = dacc[r];
        }
    }
    __syncthreads();
    for (int e = tid; e < 512; e += 256)
        atomicAdd(numer + (size_t)b * 512 + e, red[e] + red[512 + e] + red[1024 + e] + red[1536 + e]);
    if (tid < 8)
        atomicAdd(denom + b * 8 + tid, dred[tid] + dred[8 + tid] + dred[16 + tid] + dred[24 + tid]);
}

// ---------------- GRU + MLP + next q' + zero other numer ----------------
__global__ __launch_bounds__(256) void gru_q_kernel(
    const float* __restrict__ numerX, const float* __restrict__ denom,
    const float* __restrict__ slotsIn,
    const float* __restrict__ vwT, const float* __restrict__ wihT, const float* __restrict__ whhT,
    const float* __restrict__ w1T, const float* __restrict__ w2T,
    const float* __restrict__ bih, const float* __restrict__ bhh,
    const float* __restrict__ nrw, const float* __restrict__ nrb,
    const float* __restrict__ b2,
    const float* __restrict__ qwT, const float* __restrict__ k_w,
    const float* __restrict__ nsw, const float* __restrict__ nsb,
    float* __restrict__ slotsOut, unsigned short* __restrict__ qb,
    float* __restrict__ zbuf)
{
    const int tid = threadIdx.x, lane = tid & 63;
    const int row = blockIdx.x * 4 + (tid >> 6);
    float nx = numerX[row * 64 + lane];
    float xp = 0.f;
    #pragma unroll 8
    for (int i = 0; i < 64; ++i) xp = fmaf(bcastlane(nx, i), vwT[i * 64 + lane], xp);
    float x = xp / denom[row];
    float h = slotsIn[row * 64 + lane];
    float air = 0, aiz = 0, ain = 0, ahr = 0, ahz = 0, ahn = 0;
    #pragma unroll 8
    for (int i = 0; i < 64; ++i) {
        float xi = bcastlane(x, i), hi = bcastlane(h, i);
        const float* wi = wihT + i * 192;
        const float* wh = whhT + i * 192;
        air = fmaf(xi, wi[lane], air);
        aiz = fmaf(xi, wi[64 + lane], aiz);
        ain = fmaf(xi, wi[128 + lane], ain);
        ahr = fmaf(hi, wh[lane], ahr);
        ahz = fmaf(hi, wh[64 + lane], ahz);
        ahn = fmaf(hi, wh[128 + lane], ahn);
    }
    air += bih[lane]; aiz += bih[64 + lane]; ain += bih[128 + lane];
    ahr += bhh[lane]; ahz += bhh[64 + lane]; ahn += bhh[128 + lane];
    float r = 1.f / (1.f + __expf(-(air + ahr)));
    float z = 1.f / (1.f + __expf(-(aiz + ahz)));
    float n = tanhf(ain + r * ahn);
    float hn = (1.f - z) * n + z * h;
    float m = warp_red_sum(hn) * (1.0f / 64.0f);
    float dx = hn - m;
    float var = warp_red_sum(dx * dx) * (1.0f / 64.0f);
    float u = dx * rsqrtf(var + 1e-5f) * nrw[lane] + nrb[lane];
    float o0 = 0.f, o1 = 0.f;
    #pragma unroll 8
    for (int i = 0; i < 64; ++i) {
        float ui = bcastlane(u, i);
        const float* w1r = w1T + i * 128;
        o0 = fmaf(ui, w1r[lane], o0);
        o1 = fmaf(ui, w1r[64 + lane], o1);
    }
    o0 = fmaxf(o0, 0.f); o1 = fmaxf(o1, 0.f);
    float y = 0.f;
    #pragma unroll 8
    for (int j = 0; j < 64; ++j) y = fmaf(bcastlane(o0, j), w2T[j * 64 + lane], y);
    #pragma unroll 8
    for (int j = 0; j < 64; ++j) y = fmaf(bcastlane(o1, j), w2T[(64 + j) * 64 + lane], y);
    y += b2[lane];
    float out = hn + y;
    slotsOut[row * 64 + lane] = out;
    float m2 = warp_red_sum(out) * (1.0f / 64.0f);
    float dx2 = out - m2;
    float var2 = warp_red_sum(dx2 * dx2) * (1.0f / 64.0f);
    float u2 = dx2 * rsqrtf(var2 + 1e-5f) * nsw[lane] + nsb[lane];
    float q = 0.f;
    #pragma unroll 8
    for (int i = 0; i < 64; ++i) q = fmaf(bcastlane(u2, i), qwT[i * 64 + lane], q);
    float qp = 0.f;
    #pragma unroll 8
    for (int o = 0; o < 64; ++o) qp = fmaf(bcastlane(q, o), k_w[o * 64 + lane], qp);
    qb[row * 64 + lane] = bfu(qp * 0.125f);
    int g = blockIdx.x * 256 + tid;
    for (int j = g; j < 66560; j += 65536) zbuf[j] = 0.f;
}

// ---------------- final renorm of w output ----------------
__global__ __launch_bounds__(256) void renorm_kernel(float* __restrict__ wout,
                                                     const float* __restrict__ denom)
{
    const size_t i4 = (size_t)blockIdx.x * blockDim.x + threadIdx.x;
    const size_t b = i4 >> 13;
    const int half = (int)(i4 & 1);
    float4 v = reinterpret_cast<float4*>(wout)[i4];
    const float4 dv = reinterpret_cast<const float4*>(denom)[b * 2 + half];
    v.x /= dv.x; v.y /= dv.y; v.z /= dv.z; v.w /= dv.w;
    reinterpret_cast<float4*>(wout)[i4] = v;
}

extern "C" void kernel_launch(void* const* d_in, const int* in_sizes, int n_in,
                              void* d_out, int out_size, void* d_ws, size_t ws_size,
                              hipStream_t stream)
{
    const float* inputs  = (const float*)d_in[0];
    const float* eps_n   = (const float*)d_in[1];
    const float* mu      = (const float*)d_in[2];
    const float* lv      = (const float*)d_in[3];
    const float* k_w     = (const float*)d_in[4];
    const float* v_w     = (const float*)d_in[5];
    const float* q_w     = (const float*)d_in[6];
    const float* ni_w    = (const float*)d_in[7];
    const float* ni_b    = (const float*)d_in[8];
    const float* ns_w    = (const float*)d_in[9];
    const float* ns_b    = (const float*)d_in[10];
    const float* nr_w    = (const float*)d_in[11];
    const float* nr_b    = (const float*)d_in[12];
    const float* gru_wih = (const float*)d_in[13];
    const float* gru_whh = (const float*)d_in[14];
    const float* gru_bih = (const float*)d_in[15];
    const float* gru_bhh = (const float*)d_in[16];
    const float* mlp_w1  = (const float*)d_in[17];
    const float* mlp_w2  = (const float*)d_in[18];
    const float* mlp_b2  = (const float*)d_in[19];

    char* wsb = (char*)d_ws;
    unsigned short* xb  = (unsigned short*)wsb;                    // [B][N][64] bf16 (LN'd X)
    unsigned short* xbt = (unsigned short*)(wsb + 67108864);       // [B][64][N] bf16 (X^T)
    float* f      = (float*)(wsb + 134217728);
    float* slotsA = f;                                   // 65536
    float* slotsB = f + 65536;                           // 65536
    unsigned short* qb = (unsigned short*)(f + 131072);  // 65536 bf16 (q')
    float* numer0 = f + 163840;                          // 65536
    float* denom0 = f + 229376;                          // 1024
    float* numer1 = f + 230400;                          // 65536
    float* denom1 = f + 295936;                          // 1024
    float* vwT    = f + 296960;                          // 4096
    float* qwT    = f + 301056;                          // 4096
    float* wihT   = f + 305152;                          // 12288
    float* whhT   = f + 317440;                          // 12288
    float* w1T    = f + 329728;                          // 8192
    float* w2T    = f + 337920;                          // 8192

    float* out_slots = (float*)d_out;
    float* out_w     = out_slots + 65536;

    prep_kernel<<<64, 256, 0, stream>>>(v_w, q_w, gru_wih, gru_whh, mlp_w1, mlp_w2,
                                        vwT, qwT, wihT, whhT, w1T, w2T);
    init_q_kernel<<<256, 256, 0, stream>>>(eps_n, mu, lv, qwT, k_w, ns_w, ns_b,
                                           slotsA, qb, numer0);
    phase_a_ln<<<4096, 256, 0, stream>>>(inputs, ni_w, ni_b, xb, xbt);

    float* cur = slotsA;
    float* numers[2] = {numer0, numer1};
    float* denoms[2] = {denom0, denom1};
    for (int step = 0; step < 4; ++step) {
        int pb = step & 1;
        attn_mfma<<<dim3(8, 128), 256, 0, stream>>>((const __hip_bfloat16*)xb, xbt, qb,
                                                    numers[pb], denoms[pb],
                                                    step == 3 ? out_w : nullptr);
        float* nxt = (step == 3) ? out_slots : ((step & 1) ? slotsA : slotsB);
        gru_q_kernel<<<256, 256, 0, stream>>>(numers[pb], denoms[pb], cur,
                                              vwT, wihT, whhT, w1T, w2T,
                                              gru_bih, gru_bhh, nr_w, nr_b, mlp_b2,
                                              qwT, k_w, ns_w, ns_b,
                                              nxt, qb, numers[1 - pb]);
        cur = nxt;
    }
    renorm_kernel<<<4096, 256, 0, stream>>>(out_w, denom1);
}